// Round 4
// baseline (635.110 us; speedup 1.0000x reference)
//
#include <hip/hip_runtime.h>
#include <stdint.h>

#define BATCH 32
#define SEQ   2048
#define HDIM  1024

typedef short short8 __attribute__((ext_vector_type(8)));
typedef float f32x4 __attribute__((ext_vector_type(4)));

__device__ __forceinline__ unsigned short f2b(float f) {
    unsigned u = __float_as_uint(f);
    u += 0x7FFFu + ((u >> 16) & 1u);   // round-to-nearest-even
    return (unsigned short)(u >> 16);
}
// pack hi16(a) | hi16(b)<<16 in one v_perm_b32 (bf16 truncation)
__device__ __forceinline__ unsigned pk_bf16(float a, float b) {
    return __builtin_amdgcn_perm(__float_as_uint(b), __float_as_uint(a), 0x07060302u);
}
__device__ __forceinline__ float fast_tanh(float x) {
    float ex = __expf(2.0f * x);
    return 1.0f - 2.0f / (ex + 1.0f);
}
__device__ __forceinline__ void gl2lds16(const unsigned short* g, unsigned short* l) {
    __builtin_amdgcn_global_load_lds(
        (const __attribute__((address_space(1))) unsigned int*)g,
        (__attribute__((address_space(3))) unsigned int*)l, 16, 0, 0);
}

// ---------------------------------------------------------------------------
// Kernel 1: per k-row (grid=1024): We row -> bf16 (RNE); qb = hidden.Wh^T + b;
// zero scores.
// ---------------------------------------------------------------------------
__global__ __launch_bounds__(256) void prep_kernel(
    const float* __restrict__ hidden, const float* __restrict__ attn_w,
    const float* __restrict__ attn_b, unsigned short* __restrict__ we_bf,
    float* __restrict__ qb, float* __restrict__ scores) {
    int k = blockIdx.x;
    int tid = threadIdx.x;

    if (tid < 64) scores[(size_t)k * 64 + tid] = 0.0f;

    {
        const float4* src = (const float4*)(attn_w + (size_t)k * 2048 + 1024);
        float4 v = src[tid];
        ushort4 o;
        o.x = f2b(v.x); o.y = f2b(v.y); o.z = f2b(v.z); o.w = f2b(v.w);
        ((ushort4*)(we_bf + (size_t)k * HDIM))[tid] = o;
    }

    float part[BATCH];
#pragma unroll
    for (int b = 0; b < BATCH; ++b) part[b] = 0.0f;
    const float* wrow = attn_w + (size_t)k * 2048;
    for (int h = tid; h < HDIM; h += 256) {
        float w = wrow[h];
#pragma unroll
        for (int b = 0; b < BATCH; ++b) part[b] += w * hidden[b * HDIM + h];
    }
    __shared__ float red[4][BATCH];
    int lane = tid & 63, wv = tid >> 6;
#pragma unroll
    for (int b = 0; b < BATCH; ++b) {
        float v = part[b];
        v += __shfl_xor(v, 1);  v += __shfl_xor(v, 2);  v += __shfl_xor(v, 4);
        v += __shfl_xor(v, 8);  v += __shfl_xor(v, 16); v += __shfl_xor(v, 32);
        if (lane == 0) red[wv][b] = v;
    }
    __syncthreads();
    if (tid < BATCH) {
        float v = red[0][tid] + red[1][tid] + red[2][tid] + red[3][tid] + attn_b[k];
        qb[(size_t)tid * HDIM + k] = v;
    }
}

// ---------------------------------------------------------------------------
// Kernel 2: score GEMM, 256x256 tile, BK=32, 512 threads (8 waves, 2Mx4N),
// per-wave output 128x64 (8x4 16x16 frags). Double-buffered 64KB STATIC LDS.
// Occupancy: ~200 VGPR -> 2 waves/SIMD -> 8 waves/CU -> 1 block/CU; the
// per-tile barrier is hidden by issue-early staging only (loads issued one
// full compute iteration (~300-400 cyc) before the barrier that drains them;
// B is L2-resident, A is XCD-L2-shared for ~3 of 4 blocks per mtile).
// A: fp32 -> reg prefetch -> pk_bf16 -> swizzled ds_write_b128 (after MFMA).
// B: we_bf via global_load_lds, source pre-swizzled to match read swizzle.
// Swizzle: phys_chunk = logical_chunk ^ ((row>>1)&3). Bank audit: every LDS
// path (A ds_write_b128, A/B frag ds_read_b128) is perfectly bank-balanced
// (32 B per bank per instr = the 8-clk floor for 1 KB).
// XCD swizzle: 4 ntile-blocks of an mtile adjacent on one XCD -> A tile
// fetched from HBM ~once, served from that XCD's L2 afterwards.
// ---------------------------------------------------------------------------
__global__ __launch_bounds__(512, 2) void score_gemm_kernel(
    const float* __restrict__ enc, const unsigned short* __restrict__ we_bf,
    const float* __restrict__ qb, const float* __restrict__ v_w,
    float* __restrict__ scores) {
    __shared__ __align__(16) unsigned short As[2 * 8192];  // 32 KB
    __shared__ __align__(16) unsigned short Bs[2 * 8192];  // 32 KB

    int tid  = threadIdx.x;
    int lane = tid & 63, w = tid >> 6;     // 8 waves
    int wm = w & 1, wn = w >> 1;           // 2 x 4
    int i15 = lane & 15, q = lane >> 4;

    // XCD-aware decode: blockIdx%8 = XCD; 4 consecutive per-XCD slots share mtile
    int raw   = blockIdx.x;                // 0..1023
    int ntile = (raw >> 3) & 3;            // 0..3
    int mtile = (raw & 7) + 8 * (raw >> 5);// 0..255
    int n0 = ntile * 256;
    long gm0 = (long)mtile * 256;          // flat row base in [B*S]
    int b = mtile >> 3;

    // ---- B staging (global_load_lds), wave w: rows w*16 + (lane>>2), +128
    int brow_in = lane >> 2;                       // 0..15
    int bchunk  = (lane & 3) ^ ((lane >> 3) & 3);  // source pre-swizzle
    const unsigned short* Bg =
        we_bf + (size_t)(n0 + w * 16 + brow_in) * HDIM + bchunk * 8;

    // ---- A staging: thread -> row ra = tid>>1 (0..255), half h = tid&1
    int ra = tid >> 1, h = tid & 1;
    const float* Ag = enc + (size_t)(gm0 + ra) * HDIM + h * 16;
    int swz = (ra >> 1) & 3;
    int p0 = (2 * h) ^ swz, p1 = (2 * h + 1) ^ swz;

    f32x4 acc[8][4];
#pragma unroll
    for (int mt = 0; mt < 8; ++mt)
#pragma unroll
        for (int nt = 0; nt < 4; ++nt) acc[mt][nt] = (f32x4)0.0f;

    // frag-read offset (elements): logical chunk q at phys q^((row>>1)&3)
    int xoff = (q ^ ((i15 >> 1) & 3)) * 8;
    int arow0 = wm * 128 + i15;    // + mt*16
    int brow0 = wn * 64 + i15;     // + nt*16

    float4 pre[4];

#define STAGE(KT, BUF) do {                                                   \
        unsigned short* bd = Bs + (BUF) * 8192 + (w * 16) * 32 + lane * 8;    \
        const unsigned short* bsrc = Bg + (size_t)(KT) * 32;                  \
        gl2lds16(bsrc, bd);                                                   \
        gl2lds16(bsrc + (size_t)128 * HDIM, bd + 128 * 32);                   \
        const float4* ap = (const float4*)(Ag + (size_t)(KT) * 32);           \
        pre[0] = ap[0]; pre[1] = ap[1]; pre[2] = ap[2]; pre[3] = ap[3];       \
    } while (0)

#define DSW(BUF) do {                                                         \
        unsigned short* ad = As + (BUF) * 8192 + ra * 32;                     \
        uint4 u0, u1;                                                         \
        u0.x = pk_bf16(pre[0].x, pre[0].y); u0.y = pk_bf16(pre[0].z, pre[0].w);\
        u0.z = pk_bf16(pre[1].x, pre[1].y); u0.w = pk_bf16(pre[1].z, pre[1].w);\
        u1.x = pk_bf16(pre[2].x, pre[2].y); u1.y = pk_bf16(pre[2].z, pre[2].w);\
        u1.z = pk_bf16(pre[3].x, pre[3].y); u1.w = pk_bf16(pre[3].z, pre[3].w);\
        *(uint4*)(ad + p0 * 8) = u0;                                          \
        *(uint4*)(ad + p1 * 8) = u1;                                          \
    } while (0)

    // prologue: stage K-tile 0 into buffer 0
    STAGE(0, 0);
    DSW(0);
    __syncthreads();

#pragma unroll 2
    for (int kt = 0; kt < 32; ++kt) {
        int cur = kt & 1;
        if (kt < 31) STAGE(kt + 1, cur ^ 1);   // issue loads early (T14)

        const unsigned short* Ac = As + cur * 8192;
        const unsigned short* Bc = Bs + cur * 8192;

        short8 bf[4];
#pragma unroll
        for (int nt = 0; nt < 4; ++nt)
            bf[nt] = *(const short8*)(Bc + (brow0 + nt * 16) * 32 + xoff);

        __builtin_amdgcn_s_setprio(1);
#pragma unroll
        for (int mt = 0; mt < 8; ++mt) {
            short8 af = *(const short8*)(Ac + (arow0 + mt * 16) * 32 + xoff);
#pragma unroll
            for (int nt = 0; nt < 4; ++nt)
                acc[mt][nt] = __builtin_amdgcn_mfma_f32_16x16x32_bf16(
                    af, bf[nt], acc[mt][nt], 0, 0, 0);
        }
        __builtin_amdgcn_s_setprio(0);

        if (kt < 31) {
            DSW(cur ^ 1);        // pre[] consumed after this iter's MFMA block
            __syncthreads();     // drains B gl_lds; publishes A ds_writes
        }
    }
#undef STAGE
#undef DSW

    // epilogue: C layout col=i15 (n), row=q*4+reg (m); tanh + v-dot + n-reduce
    float sc[8][4];
#pragma unroll
    for (int mt = 0; mt < 8; ++mt)
#pragma unroll
        for (int r = 0; r < 4; ++r) sc[mt][r] = 0.0f;

#pragma unroll
    for (int nt = 0; nt < 4; ++nt) {
        int n = n0 + wn * 64 + nt * 16 + i15;
        float qv = qb[(size_t)b * HDIM + n];
        float vv = v_w[n];
#pragma unroll
        for (int mt = 0; mt < 8; ++mt)
#pragma unroll
            for (int r = 0; r < 4; ++r)
                sc[mt][r] += vv * fast_tanh(acc[mt][nt][r] + qv);
    }
#pragma unroll
    for (int mt = 0; mt < 8; ++mt)
#pragma unroll
        for (int r = 0; r < 4; ++r) {
            float v = sc[mt][r];
            v += __shfl_xor(v, 1); v += __shfl_xor(v, 2);
            v += __shfl_xor(v, 4); v += __shfl_xor(v, 8);
            if (i15 == 0)
                atomicAdd(&scores[gm0 + wm * 128 + mt * 16 + q * 4 + r], v);
        }
}

// ---------------------------------------------------------------------------
// Kernel 3: softmax over S per batch; writes attn_weights, zeroes context
// slots, copies hidden.
// ---------------------------------------------------------------------------
__global__ __launch_bounds__(256) void softmax_kernel(
    const float* __restrict__ scores, const float* __restrict__ hidden,
    float* out) {
    int b = blockIdx.x, tid = threadIdx.x;
    const float* srow = scores + (size_t)b * SEQ;
    __shared__ float redm[4];
    __shared__ float reds[4];
    int lane = tid & 63, wv = tid >> 6;

    float loc[8];
    float m = -1e30f;
#pragma unroll
    for (int i = 0; i < 8; ++i) {
        loc[i] = srow[tid + i * 256];
        m = fmaxf(m, loc[i]);
    }
#pragma unroll
    for (int d = 1; d < 64; d <<= 1) m = fmaxf(m, __shfl_xor(m, d));
    if (lane == 0) redm[wv] = m;
    __syncthreads();
    m = fmaxf(fmaxf(redm[0], redm[1]), fmaxf(redm[2], redm[3]));

    float sum = 0.0f;
#pragma unroll
    for (int i = 0; i < 8; ++i) {
        float e = __expf(loc[i] - m);
        loc[i] = e;
        sum += e;
    }
#pragma unroll
    for (int d = 1; d < 64; d <<= 1) sum += __shfl_xor(sum, d);
    if (lane == 0) reds[wv] = sum;
    __syncthreads();
    sum = reds[0] + reds[1] + reds[2] + reds[3];
    float inv = 1.0f / sum;

#pragma unroll
    for (int i = 0; i < 8; ++i)
        out[BATCH * SEQ + (size_t)b * SEQ + tid + i * 256] = loc[i] * inv;

    for (int i = tid; i < HDIM; i += 256) {
        out[(size_t)b * 2048 + i] = 0.0f;
        out[(size_t)b * 2048 + 1024 + i] = hidden[(size_t)b * HDIM + i];
    }
}

// ---------------------------------------------------------------------------
// Kernel 4: context from fp32 enc. grid = 32 b x 32 s-chunks (64 rows each)
// -> 4 blocks/CU for latency hiding. Thread handles 4 h via float4;
// atomicAdd partials.
// ---------------------------------------------------------------------------
__global__ __launch_bounds__(256) void context_kernel(
    const float* __restrict__ enc, const float* __restrict__ weights_src,
    float* out) {
    int id = blockIdx.x;
    int scid = id & 31, b = id >> 5;
    int tid = threadIdx.x;
    __shared__ float wl[64];
    if (tid < 64)
        wl[tid] = weights_src[BATCH * SEQ + (size_t)b * SEQ + scid * 64 + tid];
    __syncthreads();
    const float* ebase = enc + ((size_t)(b * SEQ + scid * 64)) * HDIM + tid * 4;
    float a0 = 0.f, a1 = 0.f, a2 = 0.f, a3 = 0.f;
#pragma unroll 8
    for (int s = 0; s < 64; ++s) {
        float4 e = *(const float4*)(ebase + (size_t)s * HDIM);
        float w = wl[s];
        a0 += w * e.x; a1 += w * e.y; a2 += w * e.z; a3 += w * e.w;
    }
    float* o = out + (size_t)b * 2048 + tid * 4;
    atomicAdd(o + 0, a0); atomicAdd(o + 1, a1);
    atomicAdd(o + 2, a2); atomicAdd(o + 3, a3);
}

// ---------------------------------------------------------------------------
extern "C" void kernel_launch(void* const* d_in, const int* in_sizes, int n_in,
                              void* d_out, int out_size, void* d_ws, size_t ws_size,
                              hipStream_t stream) {
    const float* hidden = (const float*)d_in[0];
    const float* enc    = (const float*)d_in[1];
    const float* attn_w = (const float*)d_in[2];
    const float* attn_b = (const float*)d_in[3];
    const float* v_w    = (const float*)d_in[4];
    float* out = (float*)d_out;

    char* ws = (char*)d_ws;
    unsigned short* we_bf = (unsigned short*)ws;                     // 2 MB
    float* qb     = (float*)(ws + (size_t)2097152);                  // 128 KB
    float* scores = (float*)(ws + (size_t)2097152 + 131072);         // 256 KB

    prep_kernel<<<1024, 256, 0, stream>>>(hidden, attn_w, attn_b, we_bf, qb, scores);
    score_gemm_kernel<<<1024, 512, 0, stream>>>(enc, we_bf, qb, v_w, scores);
    softmax_kernel<<<32, 256, 0, stream>>>(scores, hidden, out);
    context_kernel<<<1024, 256, 0, stream>>>(enc, out, out);
}